// Round 1
// baseline (301.497 us; speedup 1.0000x reference)
//
#include <hip/hip_runtime.h>

// ---------------------------------------------------------------------------
// 2-layer GCN on MI355X.
//   h   = relu( Dinv (A+I) Dinv (z @ W1) + b1 )
//   out =       Dinv (A+I) Dinv (h @ W2) + b2
// R10: aggregation rewritten for memory-level parallelism.
//  - fill precomputes packed per-edge (col, dinv[s]*dinv[d]) int2 -> removes
//    the dependent col->dinv gather chain from the hot loop.
//  - gather is 16B/lane (dwordx4): 32 lanes cover a D=256 row, so one wave
//    load instruction fetches 2 edges (4 for D=128). 8 edges in flight
//    (U x EPW) with independent accumulator banks; shfl_xor butterfly merge.
// 8 dispatches: memset, prep, scan, fill, gemm1, agg1, gemm2, agg2.
// ---------------------------------------------------------------------------

#define N_NODES 50000
#define N_EDGES 800000
#define D_IN    256
#define D_HID   256
#define D_OUT   128

typedef unsigned int uint32;
typedef unsigned short u16;

typedef __attribute__((ext_vector_type(8))) short bf16x8;   // MFMA A/B frag
typedef __attribute__((ext_vector_type(4))) float f32x4;    // MFMA C/D frag

__device__ __forceinline__ u16 f2bf_rne(float f) {
    union { float f; uint32 u; } c; c.f = f;
    uint32 u = c.u;
    u += 0x7FFFu + ((u >> 16) & 1u);
    return (u16)(u >> 16);
}
__device__ __forceinline__ float bf_lo(uint32 p) {
    union { uint32 u; float f; } c; c.u = p << 16; return c.f;
}
__device__ __forceinline__ float bf_hi(uint32 p) {
    union { uint32 u; float f; } c; c.u = p & 0xFFFF0000u; return c.f;
}

// ---------------- fused independent prep ----------------
// z->bf16, W1^T bf16, W2^T bf16, degree atomics WITH rank capture.

__global__ __launch_bounds__(256) void prep_kernel(const float* __restrict__ z,
                                                   const int* __restrict__ dst,
                                                   const float* __restrict__ W1,
                                                   const float* __restrict__ W2,
                                                   u16* __restrict__ zb,
                                                   u16* __restrict__ w1t,
                                                   u16* __restrict__ w2t,
                                                   int* __restrict__ cnt,
                                                   int* __restrict__ rank) {
    const int g = blockIdx.x * 256 + threadIdx.x;
    const int GT = gridDim.x * 256;

    for (int c = g; c < N_NODES * D_IN / 8; c += GT) {
        int i = c * 8;
        float4 a = *(const float4*)(z + i);
        float4 d = *(const float4*)(z + i + 4);
        uint4 pk;
        pk.x = (uint32)f2bf_rne(a.x) | ((uint32)f2bf_rne(a.y) << 16);
        pk.y = (uint32)f2bf_rne(a.z) | ((uint32)f2bf_rne(a.w) << 16);
        pk.z = (uint32)f2bf_rne(d.x) | ((uint32)f2bf_rne(d.y) << 16);
        pk.w = (uint32)f2bf_rne(d.z) | ((uint32)f2bf_rne(d.w) << 16);
        *(uint4*)(zb + i) = pk;
    }
    for (int idx = g; idx < D_IN * D_HID + D_HID * D_OUT; idx += GT) {
        if (idx < D_IN * D_HID) {
            int nrow = idx >> 8, kcol = idx & 255;
            w1t[idx] = f2bf_rne(W1[kcol * D_HID + nrow]);
        } else {
            int j = idx - D_IN * D_HID;
            int nrow = j >> 8, kcol = j & 255;
            w2t[j] = f2bf_rne(W2[kcol * D_OUT + nrow]);
        }
    }
    for (int i = g; i < N_EDGES; i += GT)
        rank[i] = atomicAdd(&cnt[dst[i]], 1);
}

// ---------------- single-block vectorized scan ----------------
// 1024 threads x int4 -> 13 rounds over 50000 elements (n % 4 == 0).

__global__ __launch_bounds__(1024) void scan_kernel(const int* __restrict__ cnt,
                                                    float* __restrict__ dinv,
                                                    int* __restrict__ row_ptr, int n) {
    __shared__ int wtot[16];
    __shared__ int carry_s;
    const int t = threadIdx.x;
    const int lane = t & 63, w = t >> 6;
    if (t == 0) carry_s = 0;
    __syncthreads();

    const int n4 = n >> 2;
    for (int base = 0; base < n4; base += 1024) {
        int i4 = base + t;
        int4 v = make_int4(0, 0, 0, 0);
        if (i4 < n4) v = ((const int4*)cnt)[i4];
        int s = v.x + v.y + v.z + v.w;
        int x = s;
        #pragma unroll
        for (int off = 1; off < 64; off <<= 1) {
            int u = __shfl_up(x, off, 64);
            if (lane >= off) x += u;
        }
        if (lane == 63) wtot[w] = x;
        __syncthreads();

        int wbase = 0;
        #pragma unroll
        for (int j = 0; j < 16; ++j) if (j < w) wbase += wtot[j];
        int excl = carry_s + wbase + x - s;
        if (i4 < n4) {
            int4 rp;
            rp.x = excl;
            rp.y = rp.x + v.x;
            rp.z = rp.y + v.y;
            rp.w = rp.z + v.z;
            ((int4*)row_ptr)[i4] = rp;
            float4 dv;
            dv.x = rsqrtf((float)(v.x + 1));
            dv.y = rsqrtf((float)(v.y + 1));
            dv.z = rsqrtf((float)(v.z + 1));
            dv.w = rsqrtf((float)(v.w + 1));
            ((float4*)dinv)[i4] = dv;
        }
        __syncthreads();
        if (t == 0) {
            int tot = 0;
            #pragma unroll
            for (int j = 0; j < 16; ++j) tot += wtot[j];
            carry_s += tot;
        }
        __syncthreads();
    }
    if (t == 0) row_ptr[n] = carry_s;
}

// ---------------- atomic-free CSR fill: packed (col, weight) ----------------

__global__ void fill_kernel(const int* __restrict__ src, const int* __restrict__ dst,
                            const int* __restrict__ rank, const int* __restrict__ row_ptr,
                            const float* __restrict__ dinv,
                            int2* __restrict__ edata, int n_edges) {
    int i = blockIdx.x * blockDim.x + threadIdx.x;
    if (i < n_edges) {
        int s = src[i], d = dst[i];
        float w = dinv[s] * dinv[d];
        edata[row_ptr[d] + rank[i]] = make_int2(s, __float_as_int(w));
    }
}

// ---------------- bf16 MFMA GEMM ----------------

template <int NT>
__global__ __launch_bounds__(256, 4) void gemm_bf16_kernel(const u16* __restrict__ A,
                                                           const u16* __restrict__ BT,
                                                           u16* __restrict__ C, int M) {
    const int K = 256;
    __shared__ short As[128 * 32];
    __shared__ short Bs[128 * 32];

    const int m0 = blockIdx.x * 128;
    const int n0 = blockIdx.y * 128;
    const int t  = threadIdx.x;
    const int w  = t >> 6;
    const int lane = t & 63;
    const int lm = lane & 15;
    const int lq = lane >> 4;
    const int wm = w & 1;
    const int wn = w >> 1;

    f32x4 acc[4][4] = {};

    for (int k0 = 0; k0 < K; k0 += 32) {
        #pragma unroll
        for (int j = 0; j < 2; ++j) {
            int c = w * 128 + j * 64 + lane;
            int row = c >> 2;
            int kc = k0 + (c & 3) * 8;
            int gm = m0 + row; if (gm >= M) gm = M - 1;
            const u16* gpa = A  + (size_t)gm * K + kc;
            const u16* gpb = BT + (size_t)(n0 + row) * K + kc;
            __builtin_amdgcn_global_load_lds(
                (const __attribute__((address_space(1))) void*)gpa,
                (__attribute__((address_space(3))) void*)(As + (w * 128 + j * 64) * 8),
                16, 0, 0);
            __builtin_amdgcn_global_load_lds(
                (const __attribute__((address_space(1))) void*)gpb,
                (__attribute__((address_space(3))) void*)(Bs + (w * 128 + j * 64) * 8),
                16, 0, 0);
        }
        __syncthreads();

        bf16x8 af[4], bf[4];
        #pragma unroll
        for (int mt = 0; mt < 4; ++mt)
            af[mt] = *(const bf16x8*)&As[(wm * 64 + mt * 16 + lm) * 32 + lq * 8];
        #pragma unroll
        for (int nt = 0; nt < 4; ++nt)
            bf[nt] = *(const bf16x8*)&Bs[(wn * 64 + nt * 16 + lm) * 32 + lq * 8];

        #pragma unroll
        for (int mt = 0; mt < 4; ++mt)
            #pragma unroll
            for (int nt = 0; nt < 4; ++nt)
                acc[mt][nt] = __builtin_amdgcn_mfma_f32_16x16x32_bf16(
                    af[mt], bf[nt], acc[mt][nt], 0, 0, 0);

        __syncthreads();
    }

    #pragma unroll
    for (int mt = 0; mt < 4; ++mt) {
        #pragma unroll
        for (int r = 0; r < 4; ++r) {
            int gm = m0 + wm * 64 + mt * 16 + lq * 4 + r;
            if (gm < M) {
                #pragma unroll
                for (int nt = 0; nt < 4; ++nt) {
                    int gn = n0 + wn * 64 + nt * 16 + lm;
                    C[(size_t)gm * NT + gn] = f2bf_rne(acc[mt][nt][r]);
                }
            }
        }
    }
}

// ---------------- Aggregation: one wave per node, wide gathers over CSR ----
// Lane covers 8 bf16 (16B). LPR = D/8 lanes cover one row; EPW = 64/LPR edges
// are fetched by a single wave load instruction. U groups of EPW edges are
// kept in flight (8 edges total) with independent accumulator banks; a
// shfl_xor butterfly merges the EPW edge groups at the end.

__device__ __forceinline__ void upd8(float* a, uint4 p, float w) {
    a[0] = fmaf(bf_lo(p.x), w, a[0]);
    a[1] = fmaf(bf_hi(p.x), w, a[1]);
    a[2] = fmaf(bf_lo(p.y), w, a[2]);
    a[3] = fmaf(bf_hi(p.y), w, a[3]);
    a[4] = fmaf(bf_lo(p.z), w, a[4]);
    a[5] = fmaf(bf_hi(p.z), w, a[5]);
    a[6] = fmaf(bf_lo(p.w), w, a[6]);
    a[7] = fmaf(bf_hi(p.w), w, a[7]);
}

template <int D, bool RELU, bool OUTBF>
__global__ __launch_bounds__(256) void aggregate_kernel(const u16* __restrict__ x,
                                                        const int* __restrict__ row_ptr,
                                                        const int2* __restrict__ edata,
                                                        const float* __restrict__ dinv,
                                                        const float* __restrict__ bias,
                                                        void* __restrict__ outp, int n_nodes) {
    constexpr int LPR = D / 8;      // lanes per row: 32 (D=256), 16 (D=128)
    constexpr int EPW = 64 / LPR;   // edges per wave load instr: 2 or 4
    constexpr int U   = 8 / EPW;    // unroll groups -> 8 edges in flight

    int node = (blockIdx.x * blockDim.x + threadIdx.x) >> 6;
    if (node >= n_nodes) return;
    const int lane = threadIdx.x & 63;
    const int grp  = lane / LPR;
    const int l    = lane % LPR;

    float acc[U][8];
    #pragma unroll
    for (int u = 0; u < U; ++u)
        #pragma unroll
        for (int j = 0; j < 8; ++j) acc[u][j] = 0.0f;

    // self loop: weight dinv^2, contributed once (grp 0 only)
    if (grp == 0) {
        float di = dinv[node];
        uint4 p = *(const uint4*)(x + (size_t)node * D + l * 8);
        upd8(acc[0], p, di * di);
    }

    const int e0 = row_ptr[node], e1 = row_ptr[node + 1];
    int e = e0;
    for (; e + U * EPW <= e1; e += U * EPW) {
        int2 q[U];
        #pragma unroll
        for (int u = 0; u < U; ++u)
            q[u] = edata[e + u * EPW + grp];
        #pragma unroll
        for (int u = 0; u < U; ++u) {
            uint4 p = *(const uint4*)(x + (size_t)q[u].x * D + l * 8);
            upd8(acc[u], p, __int_as_float(q[u].y));
        }
    }
    for (; e < e1; e += EPW) {
        int ee = e + grp;
        int2 q = (ee < e1) ? edata[ee] : make_int2(node, 0);
        uint4 p = *(const uint4*)(x + (size_t)q.x * D + l * 8);
        upd8(acc[0], p, __int_as_float(q.y));
    }

    float v[8];
    #pragma unroll
    for (int j = 0; j < 8; ++j) {
        float s = acc[0][j];
        #pragma unroll
        for (int u = 1; u < U; ++u) s += acc[u][j];
        v[j] = s;
    }

    // merge the EPW edge groups (they hold identical column slices)
    #pragma unroll
    for (int m = LPR; m < 64; m <<= 1)
        #pragma unroll
        for (int j = 0; j < 8; ++j)
            v[j] += __shfl_xor(v[j], m, 64);

    if (grp == 0) {
        #pragma unroll
        for (int j = 0; j < 8; ++j) {
            float s = v[j] + bias[l * 8 + j];
            v[j] = RELU ? fmaxf(s, 0.0f) : s;
        }
        if constexpr (OUTBF) {
            u16* op = (u16*)outp + (size_t)node * D + l * 8;
            uint4 pk;
            pk.x = (uint32)f2bf_rne(v[0]) | ((uint32)f2bf_rne(v[1]) << 16);
            pk.y = (uint32)f2bf_rne(v[2]) | ((uint32)f2bf_rne(v[3]) << 16);
            pk.z = (uint32)f2bf_rne(v[4]) | ((uint32)f2bf_rne(v[5]) << 16);
            pk.w = (uint32)f2bf_rne(v[6]) | ((uint32)f2bf_rne(v[7]) << 16);
            *(uint4*)op = pk;
        } else {
            float* op = (float*)outp + (size_t)node * D + l * 8;
            float4 a = make_float4(v[0], v[1], v[2], v[3]);
            float4 b = make_float4(v[4], v[5], v[6], v[7]);
            *(float4*)op = a;
            *(float4*)(op + 4) = b;
        }
    }
}

// ---------------- launcher ----------------

extern "C" void kernel_launch(void* const* d_in, const int* in_sizes, int n_in,
                              void* d_out, int out_size, void* d_ws, size_t ws_size,
                              hipStream_t stream) {
    const float* z  = (const float*)d_in[0];
    const int*   ei = (const int*)d_in[1];
    const float* W1 = (const float*)d_in[2];
    const float* b1 = (const float*)d_in[3];
    const float* W2 = (const float*)d_in[4];
    const float* b2 = (const float*)d_in[5];
    float* out = (float*)d_out;

    const int Nn = N_NODES, E = N_EDGES;
    const int* srcp = ei;
    const int* dstp = ei + E;

    char* ws = (char*)d_ws;
    size_t off = 0;
    auto alloc = [&](size_t bytes) -> char* {
        char* p = ws + off;
        off += (bytes + 511) & ~(size_t)511;
        return p;
    };
    u16*   zb     = (u16*)  alloc((size_t)Nn * D_IN * 2);
    u16*   w1t    = (u16*)  alloc((size_t)D_IN * D_HID * 2);
    u16*   w2t    = (u16*)  alloc((size_t)D_HID * D_OUT * 2);
    u16*   x1b    = (u16*)  alloc((size_t)Nn * D_HID * 2);
    u16*   hb     = (u16*)  alloc((size_t)Nn * D_HID * 2);
    u16*   h2b    = (u16*)  alloc((size_t)Nn * D_OUT * 2);
    int*   cnt    = (int*)  alloc((size_t)Nn * 4);
    float* dinv   = (float*)alloc((size_t)Nn * 4);
    int*   row_ptr= (int*)  alloc((size_t)(Nn + 1) * 4);
    int*   rank   = (int*)  alloc((size_t)E * 4);
    int2*  edata  = (int2*) alloc((size_t)E * 8);

    hipMemsetAsync(cnt, 0, (size_t)Nn * 4, stream);
    prep_kernel<<<1024, 256, 0, stream>>>(z, dstp, W1, W2, zb, w1t, w2t, cnt, rank);
    scan_kernel<<<1, 1024, 0, stream>>>(cnt, dinv, row_ptr, Nn);
    fill_kernel<<<(E + 255) / 256, 256, 0, stream>>>(srcp, dstp, rank, row_ptr, dinv, edata, E);
    {
        dim3 grid((Nn + 127) / 128, D_HID / 128);
        gemm_bf16_kernel<D_HID><<<grid, 256, 0, stream>>>(zb, w1t, x1b, Nn);
    }
    {
        int blocks = (Nn + 3) / 4;     // one wave per node
        aggregate_kernel<D_HID, true, true><<<blocks, 256, 0, stream>>>(x1b, row_ptr, edata, dinv, b1, hb, Nn);
    }
    {
        dim3 grid((Nn + 127) / 128, D_OUT / 128);
        gemm_bf16_kernel<D_OUT><<<grid, 256, 0, stream>>>(hb, w2t, h2b, Nn);
    }
    {
        int blocks = (Nn + 3) / 4;
        aggregate_kernel<D_OUT, false, false><<<blocks, 256, 0, stream>>>(h2b, row_ptr, edata, dinv, b2, out, Nn);
    }
}